// Round 5
// baseline (2015.275 us; speedup 1.0000x reference)
//
#include <hip/hip_runtime.h>

typedef __attribute__((ext_vector_type(8))) _Float16 f16x8;
typedef __attribute__((ext_vector_type(4))) float    f32x4;

#define HD    256
#define CIN   16
#define TIN   48
#define TOUT  24
#define COUT  8
#define MB    64            // batch rows per block (2x r4: halves weight-stream demand)
#define KPAD  296           // padded row stride (halves) for hF
#define KT_ENC 9            // K = 288 (h 256 | x 16 | pad 16)
#define KT_DEC 8            // K = 256
#define WE_HALVES (KT_ENC*4*16*512)   // 294912
#define WD_HALVES (KT_DEC*4*16*512)   // 262144
#define PREP_TOTAL (WE_HALVES + WD_HALVES)

template <int N> struct KTag { static constexpr int val = N; };

// Fragment-major fp16 weights: frag id = kt*64 + g*16 + ntile, each frag is
// 64 lanes x 8 halves with b_frag[lane][s] = W[k = kt*32 + (lane>>4)*8 + s]
//                                             [col = g*256 + ntile*16 + (lane&15)]
__global__ void prep_frags(const float* __restrict__ enc_Wih,
                           const float* __restrict__ enc_Whh,
                           const float* __restrict__ dec_Whh,
                           _Float16* __restrict__ wf)
{
    int p = blockIdx.x * blockDim.x + threadIdx.x;
    if (p >= PREP_TOTAL) return;
    int lane = (p >> 3) & 63;
    int s    = p & 7;
    int kq   = ((lane >> 4) << 3) + s;
    int l15  = lane & 15;
    float v;
    if (p < WE_HALVES) {
        int frag = p >> 9;
        int kt = frag >> 6, g = (frag >> 4) & 3, ntile = frag & 15;
        int k   = kt * 32 + kq;
        int row = g * 256 + ntile * 16 + l15;
        v = 0.0f;
        if (k < 256)      v = enc_Whh[row * 256 + k];
        else if (k < 272) v = enc_Wih[row * 16 + (k - 256)];
    } else {
        int q = p - WE_HALVES;
        int frag = q >> 9;
        int kt = frag >> 6, g = (frag >> 4) & 3, ntile = frag & 15;
        int k   = kt * 32 + kq;
        int row = g * 256 + ntile * 16 + l15;
        v = dec_Whh[row * 256 + k];
    }
    wf[p] = (_Float16)v;
}

__device__ __forceinline__ float sigm(float v) {
    return __builtin_amdgcn_rcpf(1.0f + __expf(-v));
}
__device__ __forceinline__ float tanh_f(float v) {
    return 1.0f - 2.0f * __builtin_amdgcn_rcpf(1.0f + __expf(2.0f * v));
}

// grid = 128 blocks, 1024 threads = 16 waves (4/SIMD). Wave w owns ntile w
// (unit-columns [w*16, w*16+16)) for all 4 gates and FOUR 16-row M-tiles.
// acc = 4 mt x 4 gates x f32x4 = 64 VGPRs.
__global__ __launch_bounds__(1024, 4) void seq2seq_mfma(
    const float* __restrict__ x,
    const _Float16* __restrict__ wf,
    const float* __restrict__ enc_b,
    const float* __restrict__ dec_b,
    const float* __restrict__ denseW,
    const float* __restrict__ denseb,
    float* __restrict__ out)
{
    __shared__ __align__(16) _Float16 hF[MB * KPAD];          // 37 KB
    __shared__ __align__(16) _Float16 xs[2][MB * CIN * 8];    // 32 KB
    __shared__ __align__(16) float    outS[MB * COUT * TOUT]; // 48 KB

    const int tid  = threadIdx.x;
    const int w    = tid >> 6;       // 0..15 = ntile
    const int lane = tid & 63;
    const int quad = lane >> 4;
    const int l15  = lane & 15;
    const int n0   = blockIdx.x * MB;

    float bE[4], bD[4];
    #pragma unroll
    for (int g = 0; g < 4; ++g) {
        int col = w * 16 + l15;
        bE[g] = enc_b[g * 256 + col];
        bD[g] = dec_b[g * 256 + col];
    }

    auto loadchunk = [&](int wd) {   // stage x[:, :, wd*8 .. wd*8+8) -> xs[wd&1]
        int m = tid >> 4, c = tid & 15;   // 64 x 16 = 1024 threads
        const float* xp = x + (size_t)(n0 + m) * (CIN * TIN) + c * TIN + wd * 8;
        float4 v0 = *(const float4*)xp;
        float4 v1 = *(const float4*)(xp + 4);
        f16x8 hv = { (_Float16)v0.x, (_Float16)v0.y, (_Float16)v0.z, (_Float16)v0.w,
                     (_Float16)v1.x, (_Float16)v1.y, (_Float16)v1.z, (_Float16)v1.w };
        *(f16x8*)(&xs[wd & 1][m * (CIN * 8) + c * 8]) = hv;
    };
    auto xcopy = [&](int t) {        // xs -> hF x-slot for step t
        int m = tid >> 4, c = tid & 15;
        hF[m * KPAD + 256 + c] = xs[(t >> 3) & 1][m * (CIN * 8) + c * 8 + (t & 7)];
    };

    for (int i = tid; i < MB * KPAD; i += 1024) hF[i] = (_Float16)0.0f;
    loadchunk(0);
    __syncthreads();
    xcopy(0);
    __syncthreads();

    f32x4 acc[4][4];        // [Mtile][gate]
    float cst[4][4];        // c-state, C-frag layout rows
    #pragma unroll
    for (int mt = 0; mt < 4; ++mt)
        #pragma unroll
        for (int r = 0; r < 4; ++r) cst[mt][r] = 0.0f;

    const f16x8* Ap[4];
    #pragma unroll
    for (int mt = 0; mt < 4; ++mt)
        Ap[mt] = (const f16x8*)(hF + (mt * 16 + l15) * KPAD);
    const f16x8* WpE = (const f16x8*)wf + w * 64 + lane;
    const f16x8* WpD = (const f16x8*)(wf + WE_HALVES) + w * 64 + lane;

    auto gemm = [&](auto kt_tag, const f16x8* __restrict__ Wp, const float (&bias)[4]) {
        constexpr int KT = decltype(kt_tag)::val;
        #pragma unroll
        for (int mt = 0; mt < 4; ++mt)
            #pragma unroll
            for (int g = 0; g < 4; ++g) {
                float b = bias[g];
                f32x4 bv = {b, b, b, b};
                acc[mt][g] = bv;
            }
        #pragma unroll
        for (int kt = 0; kt < KT; ++kt) {
            f16x8 a0 = Ap[0][kt * 4 + quad];
            f16x8 a1 = Ap[1][kt * 4 + quad];
            f16x8 a2 = Ap[2][kt * 4 + quad];
            f16x8 a3 = Ap[3][kt * 4 + quad];
            #pragma unroll
            for (int g = 0; g < 4; ++g) {
                f16x8 bf = Wp[(kt * 4 + g) * 1024];   // frag (kt*64 + g*16 + w)
                acc[0][g] = __builtin_amdgcn_mfma_f32_16x16x32_f16(a0, bf, acc[0][g], 0, 0, 0);
                acc[1][g] = __builtin_amdgcn_mfma_f32_16x16x32_f16(a1, bf, acc[1][g], 0, 0, 0);
                acc[2][g] = __builtin_amdgcn_mfma_f32_16x16x32_f16(a2, bf, acc[2][g], 0, 0, 0);
                acc[3][g] = __builtin_amdgcn_mfma_f32_16x16x32_f16(a3, bf, acc[3][g], 0, 0, 0);
            }
        }
    };

    auto pointwise = [&]() {
        int col = w * 16 + l15;
        #pragma unroll
        for (int mt = 0; mt < 4; ++mt)
            #pragma unroll
            for (int r = 0; r < 4; ++r) {
                float iv = sigm(acc[mt][0][r]);
                float fv = sigm(acc[mt][1][r]);
                float gv = tanh_f(acc[mt][2][r]);
                float ov = sigm(acc[mt][3][r]);
                float cn = fmaf(fv, cst[mt][r], iv * gv);
                cst[mt][r] = cn;
                float hv = ov * tanh_f(cn);
                hF[(mt * 16 + quad * 4 + r) * KPAD + col] = (_Float16)hv;
            }
    };

    // ================= encoder =================
    for (int t = 0; t < TIN; ++t) {
        gemm(KTag<KT_ENC>{}, WpE, bE);
        __syncthreads();              // all A-frag reads done
        pointwise();                  // write h_t
        if ((t & 7) == 0 && (t >> 3) + 1 < 6) loadchunk((t >> 3) + 1);
        if (t + 1 < TIN) xcopy(t + 1);
        __syncthreads();
    }

    // ================= decoder (c resets to 0) =================
    #pragma unroll
    for (int mt = 0; mt < 4; ++mt)
        #pragma unroll
        for (int r = 0; r < 4; ++r) cst[mt][r] = 0.0f;

    for (int t = 0; t < TOUT; ++t) {
        gemm(KTag<KT_DEC>{}, WpD, bD);
        __syncthreads();
        pointwise();
        __syncthreads();
        // dense epilogue -> LDS out buffer (threads 0..511). hF is read-only
        // until the next step's post-gemm barrier -> race-free.
        if (tid < MB * COUT) {
            int m = tid >> 3, o = tid & 7;
            const float* wr = denseW + (t * COUT + o) * HD;
            float s = denseb[t * COUT + o];
            #pragma unroll 4
            for (int j8 = 0; j8 < 32; ++j8) {
                f16x8 hv  = *(const f16x8*)(hF + m * KPAD + j8 * 8);
                float4 w0 = *(const float4*)(wr + j8 * 8);
                float4 w1 = *(const float4*)(wr + j8 * 8 + 4);
                s = fmaf((float)hv[0], w0.x, s);
                s = fmaf((float)hv[1], w0.y, s);
                s = fmaf((float)hv[2], w0.z, s);
                s = fmaf((float)hv[3], w0.w, s);
                s = fmaf((float)hv[4], w1.x, s);
                s = fmaf((float)hv[5], w1.y, s);
                s = fmaf((float)hv[6], w1.z, s);
                s = fmaf((float)hv[7], w1.w, s);
            }
            outS[m * (COUT * TOUT) + o * TOUT + t] = s;
        }
    }

    // ================= coalesced output flush =================
    __syncthreads();
    {
        const float4* src = (const float4*)outS;
        float4* dst = (float4*)(out + (size_t)n0 * (COUT * TOUT));
        for (int i = tid; i < MB * COUT * TOUT / 4; i += 1024)
            dst[i] = src[i];
    }
}

extern "C" void kernel_launch(void* const* d_in, const int* in_sizes, int n_in,
                              void* d_out, int out_size, void* d_ws, size_t ws_size,
                              hipStream_t stream) {
    const float* x       = (const float*)d_in[0];
    const float* enc_Wih = (const float*)d_in[1];
    const float* enc_Whh = (const float*)d_in[2];
    const float* enc_b   = (const float*)d_in[3];
    const float* dec_Whh = (const float*)d_in[4];
    const float* dec_b   = (const float*)d_in[5];
    const float* denseW  = (const float*)d_in[6];
    const float* denseb  = (const float*)d_in[7];
    float* out = (float*)d_out;
    _Float16* wf = (_Float16*)d_ws;   // 1.09 MB fragment-major fp16 weights

    prep_frags<<<(PREP_TOTAL + 255) / 256, 256, 0, stream>>>(enc_Wih, enc_Whh, dec_Whh, wf);
    seq2seq_mfma<<<8192 / MB, 1024, 0, stream>>>(x, wf, enc_b, dec_b, denseW, denseb, out);
}